// Round 1
// baseline (127.066 us; speedup 1.0000x reference)
//
#include <hip/hip_runtime.h>
#include <math.h>

// Problem constants (NUM_TILES=32, N_HEAD=4, D_MODEL=256, B=4)
#define TT   1024          // T = NUM_TILES^2
#define DD   256           // D_MODEL
#define KN   63            // neighbors per token
#define BB   4             // batch
#define MM   (BB * TT)     // 4096 rows in the projection GEMMs

// ---------------------------------------------------------------------------
// proj_kernel: y = x @ W^T for W in {Wq,Wk,Wv}; fused epilogue:
//   z==0 -> P  = sigmoid(y)
//   z==1 -> EK = exp(y)
//   z==2 -> V  = y
// Tiled f32 GEMM: 64x64 output tile per block, BK=64, 256 threads, 4x4/thread.
// ---------------------------------------------------------------------------
__global__ __launch_bounds__(256) void proj_kernel(
    const float* __restrict__ x,
    const float* __restrict__ Wq,
    const float* __restrict__ Wk,
    const float* __restrict__ Wv,
    float* __restrict__ P,
    float* __restrict__ EK,
    float* __restrict__ V)
{
    const int z = blockIdx.z;
    const float* __restrict__ W = (z == 0) ? Wq : (z == 1) ? Wk : Wv;
    float* __restrict__ outbuf  = (z == 0) ? P  : (z == 1) ? EK : V;

    __shared__ float xs[64][65];   // +1 pad
    __shared__ float ws[64][65];

    const int tid = threadIdx.x;
    const int tx  = tid & 15;      // 0..15 -> 4 output cols each
    const int ty  = tid >> 4;      // 0..15 -> 4 output rows each
    const int m0  = blockIdx.x * 64;
    const int n0  = blockIdx.y * 64;

    float acc[4][4] = {};

    for (int kk = 0; kk < DD; kk += 64) {
        // Stage 64x64 tiles of x and W (row-major, stride 256), float4 loads.
        #pragma unroll
        for (int i = 0; i < 4; ++i) {
            const int l  = tid + 256 * i;    // 0..1023 (float4 slots)
            const int r  = l >> 4;           // row 0..63
            const int c4 = l & 15;           // float4 col 0..15
            float4 a = *reinterpret_cast<const float4*>(
                &x[(size_t)(m0 + r) * DD + kk + c4 * 4]);
            xs[r][c4 * 4 + 0] = a.x; xs[r][c4 * 4 + 1] = a.y;
            xs[r][c4 * 4 + 2] = a.z; xs[r][c4 * 4 + 3] = a.w;
            float4 b = *reinterpret_cast<const float4*>(
                &W[(size_t)(n0 + r) * DD + kk + c4 * 4]);
            ws[r][c4 * 4 + 0] = b.x; ws[r][c4 * 4 + 1] = b.y;
            ws[r][c4 * 4 + 2] = b.z; ws[r][c4 * 4 + 3] = b.w;
        }
        __syncthreads();

        #pragma unroll
        for (int k = 0; k < 64; ++k) {
            float a[4], b[4];
            #pragma unroll
            for (int i = 0; i < 4; ++i) a[i] = xs[ty * 4 + i][k];
            #pragma unroll
            for (int j = 0; j < 4; ++j) b[j] = ws[tx * 4 + j][k];
            #pragma unroll
            for (int i = 0; i < 4; ++i)
                #pragma unroll
                for (int j = 0; j < 4; ++j)
                    acc[i][j] += a[i] * b[j];
        }
        __syncthreads();
    }

    // Epilogue with fused transcendentals.
    #pragma unroll
    for (int i = 0; i < 4; ++i) {
        const int r = m0 + ty * 4 + i;
        #pragma unroll
        for (int j = 0; j < 4; ++j) {
            const int c = n0 + tx * 4 + j;
            float v = acc[i][j];
            if (z == 0)      v = 1.0f / (1.0f + __expf(-v));
            else if (z == 1) v = __expf(v);
            outbuf[(size_t)r * DD + c] = v;
        }
    }
}

// ---------------------------------------------------------------------------
// gather_kernel: one block per (b,t); thread tid owns dim j = tid (0..255).
//   num_j = sum_k ew[t,k] * EK[b,idx[t,k],j] * V[b,idx[t,k],j]
//   den_j = sum_k ew[t,k] * EK[b,idx[t,k],j]
//   out[b,t,j] = P[b,t,j] * num_j / den_j
// ---------------------------------------------------------------------------
__global__ __launch_bounds__(256) void gather_kernel(
    const float* __restrict__ P,
    const float* __restrict__ EK,
    const float* __restrict__ V,
    const float* __restrict__ wbias,
    const int*   __restrict__ kidx,
    float* __restrict__ out)
{
    const int bt  = blockIdx.x;          // 0..4095
    const int b   = bt >> 10;
    const int t   = bt & (TT - 1);
    const int tid = threadIdx.x;

    __shared__ float ews[KN];
    __shared__ int   idxs[KN];
    if (tid < KN) {
        ews[tid]  = __expf(wbias[t * KN + tid]);
        idxs[tid] = kidx[t * KN + tid];
    }
    __syncthreads();

    const size_t bbase = (size_t)b * TT * DD;
    float num = 0.0f, den = 0.0f;

    #pragma unroll 7
    for (int k = 0; k < KN; ++k) {
        const float  w    = ews[k];
        const size_t base = bbase + (size_t)idxs[k] * DD + tid;
        const float  e    = EK[base];
        const float  v    = V[base];
        den += w * e;
        num += w * e * v;
    }

    const size_t o = bbase + (size_t)t * DD + tid;
    out[o] = P[o] * num / den;
}

extern "C" void kernel_launch(void* const* d_in, const int* in_sizes, int n_in,
                              void* d_out, int out_size, void* d_ws, size_t ws_size,
                              hipStream_t stream) {
    const float* x     = (const float*)d_in[0];
    const float* Wq    = (const float*)d_in[1];
    const float* Wk    = (const float*)d_in[2];
    const float* Wv    = (const float*)d_in[3];
    const float* wbias = (const float*)d_in[4];
    const int*   kidx  = (const int*)d_in[5];
    float* out = (float*)d_out;

    float* P  = (float*)d_ws;             // sigmoid(q): 4 MiB
    float* EK = P  + (size_t)MM * DD;     // exp(k):     4 MiB
    float* V  = EK + (size_t)MM * DD;     // v:          4 MiB

    dim3 g1(MM / 64, DD / 64, 3);
    proj_kernel<<<g1, dim3(256), 0, stream>>>(x, Wq, Wk, Wv, P, EK, V);

    gather_kernel<<<dim3(MM), dim3(256), 0, stream>>>(P, EK, V, wbias, kidx, out);
}

// Round 2
// 102.735 us; speedup vs baseline: 1.2368x; 1.2368x over previous
//
#include <hip/hip_runtime.h>
#include <hip/hip_bf16.h>
#include <math.h>

// Problem constants: NUM_TILES=32, N_HEAD=4 (folds away), D_MODEL=256, B=4
#define TT   1024
#define DD   256
#define KN   63
#define BB   4
#define MM   (BB * TT)     // 4096 rows
#define NW   768           // 3*256 concatenated W rows

typedef short bf16x8 __attribute__((ext_vector_type(8)));   // 8 bf16 = 4 VGPRs
typedef float f32x4  __attribute__((ext_vector_type(4)));

__device__ __forceinline__ unsigned short bf16bits(float f) {
    __hip_bfloat16 h = __float2bfloat16(f);
    return *reinterpret_cast<unsigned short*>(&h);
}
__device__ __forceinline__ float bf16tof(unsigned short u) {
    __hip_bfloat16 h;
    *reinterpret_cast<unsigned short*>(&h) = u;
    return __bfloat162float(h);
}

// ---------------------------------------------------------------------------
// prep_kernel: three jobs by block range.
//  [0,1024):     x (1M f32) -> xh, xl bf16 hi/lo split
//  [1024,1216):  Wq|Wk|Wv (196608 f32) -> Wh, Wl concatenated hi/lo
//  [1216,1472):  per-token weight build: A[t][32] (row part), Bw[t][32] (col
//                part) from exp(wbias) scattered by key_indices. Self entry
//                lands in A (appears exactly once); Bw[t][row(t)] stays 0.
// ---------------------------------------------------------------------------
__global__ __launch_bounds__(256) void prep_kernel(
    const float* __restrict__ x,  const float* __restrict__ Wq,
    const float* __restrict__ Wk, const float* __restrict__ Wv,
    const float* __restrict__ wbias, const int* __restrict__ kidx,
    __hip_bfloat16* __restrict__ xh, __hip_bfloat16* __restrict__ xl,
    __hip_bfloat16* __restrict__ Wh, __hip_bfloat16* __restrict__ Wl,
    float* __restrict__ Aw, float* __restrict__ Bw)
{
    const int bid = blockIdx.x, tid = threadIdx.x;
    if (bid < 1024) {                       // x split
        const int e = bid * 1024 + tid * 4;
        float4 v = *reinterpret_cast<const float4*>(&x[e]);
        float vf[4] = {v.x, v.y, v.z, v.w};
        ushort4 hh, ll;
        unsigned short* hp = &hh.x;
        unsigned short* lp = &ll.x;
        #pragma unroll
        for (int i = 0; i < 4; ++i) {
            unsigned short h = bf16bits(vf[i]);
            hp[i] = h;
            lp[i] = bf16bits(vf[i] - bf16tof(h));
        }
        *reinterpret_cast<ushort4*>(xh + e) = hh;
        *reinterpret_cast<ushort4*>(xl + e) = ll;
    } else if (bid < 1216) {                // W split (concatenated rows)
        const int e = (bid - 1024) * 1024 + tid * 4;
        const int zz = e >> 16;             // constant per block
        const float* __restrict__ Ws = (zz == 0) ? Wq : (zz == 1) ? Wk : Wv;
        const int off = e & 65535;
        float4 v = *reinterpret_cast<const float4*>(&Ws[off]);
        float vf[4] = {v.x, v.y, v.z, v.w};
        ushort4 hh, ll;
        unsigned short* hp = &hh.x;
        unsigned short* lp = &ll.x;
        #pragma unroll
        for (int i = 0; i < 4; ++i) {
            unsigned short h = bf16bits(vf[i]);
            hp[i] = h;
            lp[i] = bf16bits(vf[i] - bf16tof(h));
        }
        *reinterpret_cast<ushort4*>(Wh + e) = hh;
        *reinterpret_cast<ushort4*>(Wl + e) = ll;
    } else {                                // weight build, 4 tokens/block
        __shared__ float wbuf[4][64];
        const int wv = tid >> 6, lane = tid & 63;
        const int t = (bid - 1216) * 4 + wv;
        wbuf[wv][lane] = 0.0f;
        __syncthreads();
        if (lane < KN) {
            const float w  = __expf(wbias[t * KN + lane]);
            const int  idx = kidx[t * KN + lane];
            const int  ir = idx >> 5, ic = idx & 31;
            const int  rr = t >> 5;
            if (ir == rr) wbuf[wv][ic] = w;        // row neighbor (incl self)
            else          wbuf[wv][32 + ir] = w;   // column neighbor
        }
        __syncthreads();
        if (lane < 32) Aw[t * 32 + lane] = wbuf[wv][lane];
        else           Bw[t * 32 + (lane - 32)] = wbuf[wv][lane - 32 + 32];
    }
}

// ---------------------------------------------------------------------------
// proj_mfma: y = x @ Wcat^T via split-bf16 MFMA (xh*Wh + xh*Wl + xl*Wh),
// f32-equivalent precision. 128x128 tile, BK=32, 4 waves (2x2 quadrants),
// mfma_f32_16x16x32_bf16. Fused epilogue: region0 sigmoid->P, region1
// exp->E, region2 raw->V.
// LDS layout per tensor: [128 rows][4 k-slots of 16B], k-slot XOR-swizzled
// with ((row>>1)&3) so ds_read_b128 fragment reads are 2-way (free).
// ---------------------------------------------------------------------------
__device__ __forceinline__ void stage_tile(const __hip_bfloat16* __restrict__ src,
                                           char* __restrict__ lds, int tid)
{
    #pragma unroll
    for (int i = 0; i < 2; ++i) {
        const int slot = tid + i * 256;      // 0..511
        const int row = slot >> 2;           // 0..127
        const int ks  = slot & 3;            // 16B k-slot
        int4 v = *reinterpret_cast<const int4*>(src + (size_t)row * DD + ks * 8);
        *reinterpret_cast<int4*>(lds + row * 64 + ((ks ^ ((row >> 1) & 3)) << 4)) = v;
    }
}

__global__ __launch_bounds__(256) void proj_mfma(
    const __hip_bfloat16* __restrict__ xh, const __hip_bfloat16* __restrict__ xl,
    const __hip_bfloat16* __restrict__ Wh, const __hip_bfloat16* __restrict__ Wl,
    float* __restrict__ P, float* __restrict__ E, float* __restrict__ V)
{
    __shared__ char lds[32768];              // Ah | Al | Bh | Bl, 8KB each
    const int tid = threadIdx.x;
    const int lane = tid & 63, wave = tid >> 6;
    const int wr = wave >> 1, wc = wave & 1;
    const int m0 = blockIdx.x * 128;
    const int ny = blockIdx.y;               // 0..5
    const int n0 = ny * 128;

    f32x4 acc[4][4];
    #pragma unroll
    for (int i = 0; i < 4; ++i)
        #pragma unroll
        for (int j = 0; j < 4; ++j) acc[i][j] = (f32x4)0.0f;

    const int kg = lane >> 4, li = lane & 15;

    for (int kt = 0; kt < 8; ++kt) {
        const int k0 = kt * 32;
        stage_tile(xh + (size_t)m0 * DD + k0, lds,         tid);
        stage_tile(xl + (size_t)m0 * DD + k0, lds + 8192,  tid);
        stage_tile(Wh + (size_t)n0 * DD + k0, lds + 16384, tid);
        stage_tile(Wl + (size_t)n0 * DD + k0, lds + 24576, tid);
        __syncthreads();

        bf16x8 bh[4], bl[4];
        #pragma unroll
        for (int fn = 0; fn < 4; ++fn) {
            const int r   = wc * 64 + fn * 16 + li;
            const int off = r * 64 + ((kg ^ ((r >> 1) & 3)) << 4);
            bh[fn] = *reinterpret_cast<const bf16x8*>(lds + 16384 + off);
            bl[fn] = *reinterpret_cast<const bf16x8*>(lds + 24576 + off);
        }
        #pragma unroll
        for (int fm = 0; fm < 4; ++fm) {
            const int r   = wr * 64 + fm * 16 + li;
            const int off = r * 64 + ((kg ^ ((r >> 1) & 3)) << 4);
            bf16x8 ah = *reinterpret_cast<const bf16x8*>(lds + off);
            bf16x8 al = *reinterpret_cast<const bf16x8*>(lds + 8192 + off);
            #pragma unroll
            for (int fn = 0; fn < 4; ++fn) {
                acc[fm][fn] = __builtin_amdgcn_mfma_f32_16x16x32_bf16(ah, bh[fn], acc[fm][fn], 0, 0, 0);
                acc[fm][fn] = __builtin_amdgcn_mfma_f32_16x16x32_bf16(ah, bl[fn], acc[fm][fn], 0, 0, 0);
                acc[fm][fn] = __builtin_amdgcn_mfma_f32_16x16x32_bf16(al, bh[fn], acc[fm][fn], 0, 0, 0);
            }
        }
        __syncthreads();
    }

    // Epilogue: C/D layout col=lane&15, row=(lane>>4)*4+j (verified mapping).
    const int region = ny >> 1;
    float* __restrict__ ob = (region == 0) ? P : (region == 1) ? E : V;
    const int ncol0 = (ny & 1) * 128;
    const int lj = (lane >> 4) << 2;
    #pragma unroll
    for (int fm = 0; fm < 4; ++fm) {
        #pragma unroll
        for (int fn = 0; fn < 4; ++fn) {
            const int mb = m0 + wr * 64 + fm * 16 + lj;
            const int cc = ncol0 + wc * 64 + fn * 16 + li;
            #pragma unroll
            for (int j = 0; j < 4; ++j) {
                float v0 = acc[fm][fn][j];
                if (region == 0)      v0 = 1.0f / (1.0f + __expf(-v0));
                else if (region == 1) v0 = __expf(v0);
                ob[(size_t)(mb + j) * DD + cc] = v0;
            }
        }
    }
}

// ---------------------------------------------------------------------------
// rowpass: block = (b, r, d-half). num_row/den_row for the 32 tokens of grid
// row r: num[t=(r,c),d] = sum_j A[t][j]*E[b,r*32+j,d]*V[...]. Writes num to
// d_out, den to Dbuf.
// ---------------------------------------------------------------------------
__global__ __launch_bounds__(256) void rowpass(
    const float* __restrict__ E, const float* __restrict__ V,
    const float* __restrict__ Aw, float* __restrict__ Nout, float* __restrict__ Dout)
{
    __shared__ float Et[32][132], Vt[32][132], At[32][36];
    const int bid = blockIdx.x, tid = threadIdx.x;
    const int dh = bid & 1, r = (bid >> 1) & 31, b = bid >> 6;
    const size_t base = ((size_t)(b * TT + r * 32)) * DD + dh * 128;

    #pragma unroll
    for (int i = 0; i < 4; ++i) {
        const int slot = tid + i * 256;
        const int row = slot >> 5, c4 = (slot & 31) * 4;
        *reinterpret_cast<f32x4*>(&Et[row][c4]) =
            *reinterpret_cast<const f32x4*>(&E[base + (size_t)row * DD + c4]);
        *reinterpret_cast<f32x4*>(&Vt[row][c4]) =
            *reinterpret_cast<const f32x4*>(&V[base + (size_t)row * DD + c4]);
    }
    {
        const int c = tid >> 3, j4 = (tid & 7) * 4;
        *reinterpret_cast<f32x4*>(&At[c][j4]) =
            *reinterpret_cast<const f32x4*>(&Aw[(size_t)(r * 32 + c) * 32 + j4]);
    }
    __syncthreads();

    const int dq = tid & 31, cg = tid >> 5;
    f32x4 num[4], den[4];
    #pragma unroll
    for (int ci = 0; ci < 4; ++ci) { num[ci] = (f32x4)0.0f; den[ci] = (f32x4)0.0f; }

    for (int j = 0; j < 32; ++j) {
        f32x4 e = *reinterpret_cast<const f32x4*>(&Et[j][dq * 4]);
        f32x4 v = *reinterpret_cast<const f32x4*>(&Vt[j][dq * 4]);
        f32x4 ev = e * v;
        #pragma unroll
        for (int ci = 0; ci < 4; ++ci) {
            const float w = At[cg * 4 + ci][j];
            den[ci] += e * w;
            num[ci] += ev * w;
        }
    }
    #pragma unroll
    for (int ci = 0; ci < 4; ++ci) {
        const size_t o = ((size_t)(b * TT + r * 32 + cg * 4 + ci)) * DD + dh * 128 + dq * 4;
        *reinterpret_cast<f32x4*>(&Nout[o]) = num[ci];
        *reinterpret_cast<f32x4*>(&Dout[o]) = den[ci];
    }
}

// ---------------------------------------------------------------------------
// colpass: block = (b, c, d-half). Adds column-part partials, then fuses the
// final out = P * (num_row+num_col) / (den_row+den_col), in-place on d_out.
// ---------------------------------------------------------------------------
__global__ __launch_bounds__(256) void colpass(
    const float* __restrict__ E, const float* __restrict__ V,
    const float* __restrict__ Bw, const float* __restrict__ P,
    const float* __restrict__ Drow, float* __restrict__ out)
{
    __shared__ float Et[32][132], Vt[32][132], Bt[32][36];
    const int bid = blockIdx.x, tid = threadIdx.x;
    const int dh = bid & 1, c = (bid >> 1) & 31, b = bid >> 6;

    #pragma unroll
    for (int i = 0; i < 4; ++i) {
        const int slot = tid + i * 256;
        const int j = slot >> 5, c4 = (slot & 31) * 4;
        const size_t g = ((size_t)(b * TT + j * 32 + c)) * DD + dh * 128 + c4;
        *reinterpret_cast<f32x4*>(&Et[j][c4]) = *reinterpret_cast<const f32x4*>(&E[g]);
        *reinterpret_cast<f32x4*>(&Vt[j][c4]) = *reinterpret_cast<const f32x4*>(&V[g]);
    }
    {
        const int rr = tid >> 3, j4 = (tid & 7) * 4;
        *reinterpret_cast<f32x4*>(&Bt[rr][j4]) =
            *reinterpret_cast<const f32x4*>(&Bw[(size_t)(rr * 32 + c) * 32 + j4]);
    }
    __syncthreads();

    const int dq = tid & 31, rg = tid >> 5;
    f32x4 num[4], den[4];
    #pragma unroll
    for (int ri = 0; ri < 4; ++ri) { num[ri] = (f32x4)0.0f; den[ri] = (f32x4)0.0f; }

    for (int j = 0; j < 32; ++j) {
        f32x4 e = *reinterpret_cast<const f32x4*>(&Et[j][dq * 4]);
        f32x4 v = *reinterpret_cast<const f32x4*>(&Vt[j][dq * 4]);
        f32x4 ev = e * v;
        #pragma unroll
        for (int ri = 0; ri < 4; ++ri) {
            const float w = Bt[rg * 4 + ri][j];
            den[ri] += e * w;
            num[ri] += ev * w;
        }
    }
    #pragma unroll
    for (int ri = 0; ri < 4; ++ri) {
        const size_t o = ((size_t)(b * TT + (rg * 4 + ri) * 32 + c)) * DD + dh * 128 + dq * 4;
        f32x4 nr = *reinterpret_cast<const f32x4*>(&out[o]);
        f32x4 dr = *reinterpret_cast<const f32x4*>(&Drow[o]);
        f32x4 p  = *reinterpret_cast<const f32x4*>(&P[o]);
        f32x4 res = p * (num[ri] + nr) / (den[ri] + dr);
        *reinterpret_cast<f32x4*>(&out[o]) = res;
    }
}

extern "C" void kernel_launch(void* const* d_in, const int* in_sizes, int n_in,
                              void* d_out, int out_size, void* d_ws, size_t ws_size,
                              hipStream_t stream) {
    const float* x     = (const float*)d_in[0];
    const float* Wq    = (const float*)d_in[1];
    const float* Wk    = (const float*)d_in[2];
    const float* Wv    = (const float*)d_in[3];
    const float* wbias = (const float*)d_in[4];
    const int*   kidx  = (const int*)d_in[5];

    // Workspace layout (~17 MB):
    float* P  = (float*)d_ws;                 // 1M f32
    float* E  = P + 1048576;                  // 1M f32
    float* V  = E + 1048576;                  // 1M f32
    float* Aw = V + 1048576;                  // 32K f32
    float* Bw = Aw + 32768;                   // 32K f32
    __hip_bfloat16* xh = (__hip_bfloat16*)(Bw + 32768);  // 1M bf16
    __hip_bfloat16* xl = xh + 1048576;                   // 1M bf16
    __hip_bfloat16* Wh = xl + 1048576;                   // 196608 bf16
    __hip_bfloat16* Wl = Wh + 196608;                    // 196608 bf16
    // Dbuf aliases xh/xl (4 MB): xh/xl are dead after proj_mfma, Dbuf is
    // first written by rowpass which runs strictly after on the same stream.
    float* Dbuf = (float*)xh;

    prep_kernel<<<1472, 256, 0, stream>>>(x, Wq, Wk, Wv, wbias, kidx,
                                          xh, xl, Wh, Wl, Aw, Bw);
    proj_mfma<<<dim3(32, 6), 256, 0, stream>>>(xh, xl, Wh, Wl, P, E, V);
    rowpass<<<256, 256, 0, stream>>>(E, V, Aw, (float*)d_out, Dbuf);
    colpass<<<256, 256, 0, stream>>>(E, V, Bw, P, Dbuf, (float*)d_out);
}